// Round 2
// baseline (555.410 us; speedup 1.0000x reference)
//
#include <hip/hip_runtime.h>
#include <cstdio>
#include <cstdint>

// RGCN block: h = BN(sum_r mean_r @ W_r + x@root + bias); PReLU; + x residual.
// Strategy: GEMM first (Y = x @ [W_0..W_7 | root]), then per-dst CSR gather of Y rows
// scaled by 1/cnt(rel,dst). BN batch stats via column atomics, fused finalize.
// NOTE: harness delivers integer inputs as int32 (edge_index int64 -> const int*).

constexpr int kN  = 50000;   // nodes
constexpr int kE  = 800000;  // edges
constexpr int kR  = 8;       // relations
constexpr int kC  = 256;     // in = out channels
constexpr int kMP = 50048;   // padded rows (391*128)
constexpr int kNC = 2304;    // 8*256 (rels) + 256 (root)
constexpr int kYC = 2048;    // Y columns (rel part only)

typedef __attribute__((ext_vector_type(8))) short bf16x8;
typedef __attribute__((ext_vector_type(4))) float f32x4;

__device__ __forceinline__ unsigned short f2bf(float f) {
  unsigned u = __builtin_bit_cast(unsigned, f);
  u = u + 0x7FFFu + ((u >> 16) & 1u);
  return (unsigned short)(u >> 16);
}
__device__ __forceinline__ float bf2f(unsigned short s) {
  unsigned u = ((unsigned)s) << 16;
  return __builtin_bit_cast(float, u);
}
__device__ __forceinline__ void gload16(const void* g, void* l) {
  __builtin_amdgcn_global_load_lds((__attribute__((address_space(1))) const void*)g,
                                   (__attribute__((address_space(3))) void*)l, 16, 0, 0);
}

// ---- phase 1: per-edge counts (cnt[rel*N+dst], deg[dst]) ----
__global__ void k_count(const int* __restrict__ ei, const float* __restrict__ ea,
                        int* __restrict__ cnt, int* __restrict__ deg) {
  int e = blockIdx.x * blockDim.x + threadIdx.x;
  if (e >= kE) return;
  int dst = ei[kE + e];
  int rel = (int)ea[(size_t)e * 5 + 4];
  if ((unsigned)dst >= (unsigned)kN || (unsigned)rel >= (unsigned)kR) return;
  atomicAdd(&cnt[rel * kN + dst], 1);
  atomicAdd(&deg[dst], 1);
}

// ---- phase 2: convert x -> bf16 (padded rows zeroed) ----
__global__ void k_convert_x(const float* __restrict__ x, unsigned short* __restrict__ xbf) {
  int i = (blockIdx.x * blockDim.x + threadIdx.x) * 4;
  if (i >= kMP * kC) return;
  float4 v;
  if (i < kN * kC) v = *(const float4*)(x + i);
  else             v = make_float4(0.f, 0.f, 0.f, 0.f);
  ushort4 o;
  o.x = f2bf(v.x); o.y = f2bf(v.y); o.z = f2bf(v.z); o.w = f2bf(v.w);
  *(ushort4*)(xbf + i) = o;
}

// ---- phase 3: convert W+root -> bf16, TRANSPOSED: wbfT[c][k], c = r*256+j (c<2048) else root col ----
__global__ void k_convert_w(const float* __restrict__ W, const float* __restrict__ root,
                            unsigned short* __restrict__ wbfT) {
  int t = blockIdx.x * blockDim.x + threadIdx.x;
  if (t >= kNC * kC) return;
  int c = t >> 8, k = t & 255;
  float v;
  if (c < kR * kC) {
    int r = c >> 8, j = c & 255;
    v = W[(size_t)r * kC * kC + (size_t)k * kC + j];
  } else {
    v = root[(size_t)k * kC + (c - kR * kC)];
  }
  wbfT[(size_t)c * kC + k] = f2bf(v);
}

// ---- phase 4: exclusive scan of deg -> off, cursor (single block) ----
__global__ void k_scan(const int* __restrict__ deg, int* __restrict__ off, int* __restrict__ cur) {
  __shared__ int ps[257];
  int t = threadIdx.x;                  // 256 threads
  int slab = (kN + 255) / 256;
  int lo = t * slab, hi = min(lo + slab, kN);
  int s = 0;
  for (int i = lo; i < hi; ++i) s += deg[i];
  ps[t] = s;
  __syncthreads();
  if (t == 0) {
    int run = 0;
    for (int i = 0; i < 256; ++i) { int tmp = ps[i]; ps[i] = run; run += tmp; }
    ps[256] = run;
  }
  __syncthreads();
  int run = ps[t];
  for (int i = lo; i < hi; ++i) { off[i] = run; cur[i] = run; run += deg[i]; }
  if (t == 0) off[kN] = ps[256];
}

// ---- phase 5: fill CSR edge records (src | rel<<16) ----
__global__ void k_fill(const int* __restrict__ ei, const float* __restrict__ ea,
                       int* __restrict__ cur, unsigned* __restrict__ ebuf) {
  int e = blockIdx.x * blockDim.x + threadIdx.x;
  if (e >= kE) return;
  int src = ei[e];
  int dst = ei[kE + e];
  int rel = (int)ea[(size_t)e * 5 + 4];
  if ((unsigned)dst >= (unsigned)kN || (unsigned)rel >= (unsigned)kR) return;
  int pos = atomicAdd(&cur[dst], 1);
  ebuf[pos] = (unsigned)src | ((unsigned)rel << 16);
}

// ---- phase 6: GEMM  [MP x 256] @ [256 x 2304] -> Y (bf16, cols<2048) / d_out (f32, root+bias) ----
__global__ __launch_bounds__(256) void k_gemm(const unsigned short* __restrict__ xbf,
                                              const unsigned short* __restrict__ wbfT,
                                              unsigned short* __restrict__ Y,
                                              float* __restrict__ out,
                                              const float* __restrict__ bias) {
  __shared__ __align__(16) unsigned short As[128 * 64];  // [row][k]
  __shared__ __align__(16) unsigned short Bs[128 * 64];  // [col][k]
  const int tid = threadIdx.x;
  const int lane = tid & 63, wv = tid >> 6;
  const int n0 = blockIdx.x * 128, m0 = blockIdx.y * 128;
  const int wm = wv >> 1, wn = wv & 1;  // 2x2 wave grid, each wave 64x64 out
  f32x4 acc[4][4] = {};

  const int srow = (lane >> 3);        // 0..7
  const int skk  = (lane & 7) * 8;     // 0..56
  for (int kt = 0; kt < 4; ++kt) {
    const int kb = kt * 64;
#pragma unroll
    for (int c = 0; c < 4; ++c) {
      int row = c * 32 + wv * 8 + srow;
      gload16(xbf  + (size_t)(m0 + row) * kC + kb + skk, &As[c * 2048 + wv * 512]);
      gload16(wbfT + (size_t)(n0 + row) * kC + kb + skk, &Bs[c * 2048 + wv * 512]);
    }
    __syncthreads();
#pragma unroll
    for (int kk = 0; kk < 64; kk += 32) {
      const int koff = kk + (lane >> 4) * 8;
      bf16x8 a[4], b[4];
#pragma unroll
      for (int i = 0; i < 4; ++i) {
        a[i] = *(const bf16x8*)&As[(wm * 64 + i * 16 + (lane & 15)) * 64 + koff];
        b[i] = *(const bf16x8*)&Bs[(wn * 64 + i * 16 + (lane & 15)) * 64 + koff];
      }
#pragma unroll
      for (int i = 0; i < 4; ++i)
#pragma unroll
        for (int j = 0; j < 4; ++j)
          acc[i][j] = __builtin_amdgcn_mfma_f32_16x16x32_bf16(a[i], b[j], acc[i][j], 0, 0, 0);
    }
    __syncthreads();
  }

  // epilogue: C/D layout col = lane&15, row = (lane>>4)*4 + r   [verified layout]
  if (n0 < kYC) {
#pragma unroll
    for (int i = 0; i < 4; ++i)
#pragma unroll
      for (int j = 0; j < 4; ++j) {
        int col = n0 + wn * 64 + j * 16 + (lane & 15);
        int rb  = m0 + wm * 64 + i * 16 + (lane >> 4) * 4;
#pragma unroll
        for (int r = 0; r < 4; ++r)
          Y[(size_t)(rb + r) * kYC + col] = f2bf(acc[i][j][r]);
      }
  } else {
#pragma unroll
    for (int i = 0; i < 4; ++i)
#pragma unroll
      for (int j = 0; j < 4; ++j) {
        int col = n0 - kYC + wn * 64 + j * 16 + (lane & 15);
        int rb  = m0 + wm * 64 + i * 16 + (lane >> 4) * 4;
        float bv = bias[col];
#pragma unroll
        for (int r = 0; r < 4; ++r) {
          int row = rb + r;
          if (row < kN) out[(size_t)row * kC + col] = acc[i][j][r] + bv;
        }
      }
  }
}

// ---- phase 7: per-dst gather: h[dst] += sum_e Y[src, rel] / cnt[rel,dst]  (1 wave / dst) ----
__global__ __launch_bounds__(256) void k_gather(const unsigned* __restrict__ ebuf,
                                                const int* __restrict__ off,
                                                const int* __restrict__ cnt,
                                                const unsigned short* __restrict__ Y,
                                                float* __restrict__ h) {
  int wid = blockIdx.x * 4 + (threadIdx.x >> 6);
  if (wid >= kN) return;
  int lane = threadIdx.x & 63;
  int e0 = off[wid], e1 = off[wid + 1];
  float a0 = 0.f, a1 = 0.f, a2 = 0.f, a3 = 0.f;
  for (int e = e0; e < e1; ++e) {
    unsigned rec = ebuf[e];
    int src = rec & 0xFFFF;
    int rel = rec >> 16;
    float sc = 1.0f / (float)cnt[rel * kN + wid];
    ushort4 v = *(const ushort4*)(Y + (size_t)src * kYC + rel * kC + lane * 4);
    a0 += sc * bf2f(v.x); a1 += sc * bf2f(v.y); a2 += sc * bf2f(v.z); a3 += sc * bf2f(v.w);
  }
  float4* hp = (float4*)(h + (size_t)wid * kC + lane * 4);
  float4 hv = *hp;
  hv.x += a0; hv.y += a1; hv.z += a2; hv.w += a3;
  *hp = hv;
}

// ---- phase 8: BN column stats ----
__global__ void k_stats(const float* __restrict__ h, float* __restrict__ cs, float* __restrict__ csq) {
  int col = threadIdx.x;  // 256
  float s = 0.f, ss = 0.f;
  for (int row = blockIdx.x; row < kN; row += gridDim.x) {
    float v = h[(size_t)row * kC + col];
    s += v; ss += v * v;
  }
  atomicAdd(&cs[col], s);
  atomicAdd(&csq[col], ss);
}

// ---- phase 9: BN normalize + PReLU + residual ----
__global__ void k_final(float* __restrict__ h, const float* __restrict__ x,
                        const float* __restrict__ cs, const float* __restrict__ csq,
                        const float* __restrict__ gamma, const float* __restrict__ beta,
                        const float* __restrict__ prelu) {
  int idx = (blockIdx.x * blockDim.x + threadIdx.x) * 4;
  if (idx >= kN * kC) return;
  int col = idx & 255;
  const float inv_n = 1.0f / (float)kN;
  float a = prelu[0];
  float4 hv = *(float4*)(h + idx);
  float4 xv = *(const float4*)(x + idx);
  float hr[4] = {hv.x, hv.y, hv.z, hv.w};
  float xr[4] = {xv.x, xv.y, xv.z, xv.w};
#pragma unroll
  for (int j = 0; j < 4; ++j) {
    int c = col + j;
    float mu  = cs[c] * inv_n;
    float var = csq[c] * inv_n - mu * mu;
    float k   = gamma[c] * rsqrtf(var + 1e-5f);
    float v   = (hr[j] - mu) * k + beta[c];
    v = v > 0.f ? v : a * v;
    hr[j] = v + xr[j];
  }
  *(float4*)(h + idx) = make_float4(hr[0], hr[1], hr[2], hr[3]);
}

extern "C" void kernel_launch(void* const* d_in, const int* in_sizes, int n_in,
                              void* d_out, int out_size, void* d_ws, size_t ws_size,
                              hipStream_t stream) {
  const float* x     = (const float*)d_in[0];
  const int*   ei    = (const int*)d_in[1];     // int64 in ref -> int32 from harness
  const float* ea    = (const float*)d_in[2];
  const float* W     = (const float*)d_in[3];
  const float* root  = (const float*)d_in[4];
  const float* bias  = (const float*)d_in[5];
  const float* gamma = (const float*)d_in[6];
  const float* beta  = (const float*)d_in[7];
  const float* prelu = (const float*)d_in[8];
  float* out = (float*)d_out;
  char* ws = (char*)d_ws;

  size_t o = 0;
  auto alloc = [&](size_t sz) { size_t r = o; o += (sz + 255) & ~(size_t)255; return r; };
  size_t xbf_o = alloc((size_t)kMP * kC * 2);
  size_t wbf_o = alloc((size_t)kNC * kC * 2);
  size_t y_o   = alloc((size_t)kMP * kYC * 2);
  size_t cnt_o = alloc((size_t)kR * kN * 4);
  size_t deg_o = alloc((size_t)kN * 4);
  size_t cs_o  = alloc(256 * 4);
  size_t csq_o = alloc(256 * 4);
  size_t zend  = o;                      // end of must-zero region
  size_t off_o = alloc((size_t)(kN + 1) * 4);
  size_t cur_o = alloc((size_t)kN * 4);
  size_t eb_o  = alloc((size_t)kE * 4);
  if (o > ws_size) {
    fprintf(stderr, "[RGCN kernel] ws too small: need %zu have %zu\n", o, ws_size);
    return;
  }

  unsigned short* xbf  = (unsigned short*)(ws + xbf_o);
  unsigned short* wbfT = (unsigned short*)(ws + wbf_o);
  unsigned short* Y    = (unsigned short*)(ws + y_o);
  int*      cnt  = (int*)(ws + cnt_o);
  int*      deg  = (int*)(ws + deg_o);
  float*    cs   = (float*)(ws + cs_o);
  float*    csq  = (float*)(ws + csq_o);
  int*      offp = (int*)(ws + off_o);
  int*      cur  = (int*)(ws + cur_o);
  unsigned* ebuf = (unsigned*)(ws + eb_o);

  hipMemsetAsync(ws + cnt_o, 0, zend - cnt_o, stream);  // cnt, deg, cs, csq
  k_count<<<(kE + 255) / 256, 256, 0, stream>>>(ei, ea, cnt, deg);
  k_convert_x<<<(kMP * kC / 4 + 255) / 256, 256, 0, stream>>>(x, xbf);
  k_convert_w<<<(kNC * kC) / 256, 256, 0, stream>>>(W, root, wbfT);
  k_scan<<<1, 256, 0, stream>>>(deg, offp, cur);
  k_fill<<<(kE + 255) / 256, 256, 0, stream>>>(ei, ea, cur, ebuf);
  k_gemm<<<dim3(kNC / 128, kMP / 128), 256, 0, stream>>>(xbf, wbfT, Y, out, bias);
  k_gather<<<(kN + 3) / 4, 256, 0, stream>>>(ebuf, offp, cnt, Y, out);
  k_stats<<<512, 256, 0, stream>>>(out, cs, csq);
  k_final<<<(kN * kC / 4) / 256, 256, 0, stream>>>(out, x, cs, csq, gamma, beta, prelu);
}

// Round 3
// 515.013 us; speedup vs baseline: 1.0784x; 1.0784x over previous
//
#include <hip/hip_runtime.h>
#include <cstdio>
#include <cstdint>

// RGCN block, aggregation-first formulation:
//   M[dst, r*256+ch] = mean_{edges (src->dst, rel=r)} x_bf16[src, ch]   (x is L3-hot, 25.6 MB)
//   A = [M | x_bf16]  (50048 x 2304),  B = [W_0..W_7 ; root]  (2304 x 256)
//   h = A @ B + bias  -> BN(batch stats) -> PReLU -> + x
// CSR grouped by (dst, rel) via counting sort; edge records are u16 src only.

constexpr int kN  = 50000;   // nodes
constexpr int kE  = 800000;  // edges
constexpr int kR  = 8;       // relations
constexpr int kC  = 256;     // channels
constexpr int kMP = 50048;   // padded rows (391*128)
constexpr int kK  = 2304;    // GEMM K = 8*256 + 256

typedef __attribute__((ext_vector_type(8))) short bf16x8;
typedef __attribute__((ext_vector_type(4))) float f32x4;
typedef __attribute__((ext_vector_type(2))) unsigned int u32x2;

__device__ __forceinline__ unsigned short f2bf(float f) {
  unsigned u = __builtin_bit_cast(unsigned, f);
  u = u + 0x7FFFu + ((u >> 16) & 1u);
  return (unsigned short)(u >> 16);
}
__device__ __forceinline__ float bf2f(unsigned short s) {
  unsigned u = ((unsigned)s) << 16;
  return __builtin_bit_cast(float, u);
}
__device__ __forceinline__ void gload16(const void* g, void* l) {
  __builtin_amdgcn_global_load_lds((__attribute__((address_space(1))) const void*)g,
                                   (__attribute__((address_space(3))) void*)l, 16, 0, 0);
}

// ---- per-edge counts: cnt[rel*N+dst], deg[dst] ----
__global__ void k_count(const int* __restrict__ ei, const float* __restrict__ ea,
                        int* __restrict__ cnt, int* __restrict__ deg) {
  int e = blockIdx.x * blockDim.x + threadIdx.x;
  if (e >= kE) return;
  int dst = ei[kE + e];
  int rel = (int)ea[(size_t)e * 5 + 4];
  if ((unsigned)dst >= (unsigned)kN || (unsigned)rel >= (unsigned)kR) return;
  atomicAdd(&cnt[rel * kN + dst], 1);
  atomicAdd(&deg[dst], 1);
}

// ---- convert x -> bf16 into A cols 2048..2303 (rows < kN; pad rows memset elsewhere) ----
__global__ void k_convert_x(const float* __restrict__ x, unsigned short* __restrict__ A) {
  int i = (blockIdx.x * blockDim.x + threadIdx.x) * 4;
  if (i >= kN * kC) return;
  int row = i >> 8, col = i & 255;
  float4 v = *(const float4*)(x + i);
  ushort4 o;
  o.x = f2bf(v.x); o.y = f2bf(v.y); o.z = f2bf(v.z); o.w = f2bf(v.w);
  *(ushort4*)(A + (size_t)row * kK + 2048 + col) = o;
}

// ---- convert W+root -> bf16 transposed: wbfT[c][k], k<2048: W[k>>8][k&255][c]; else root[k-2048][c] ----
__global__ void k_convert_w(const float* __restrict__ W, const float* __restrict__ root,
                            unsigned short* __restrict__ wbfT) {
  int t = blockIdx.x * blockDim.x + threadIdx.x;   // c*kK + k
  if (t >= kC * kK) return;
  int c = t / kK, k = t - c * kK;
  float v;
  if (k < kR * kC) {
    int r = k >> 8, kk = k & 255;
    v = W[(size_t)r * kC * kC + (size_t)kk * kC + c];
  } else {
    v = root[(size_t)(k - kR * kC) * kC + c];
  }
  wbfT[(size_t)c * kK + k] = f2bf(v);
}

// ---- exclusive scan of deg -> off (1024 threads, shfl + wave-total scan) ----
__global__ __launch_bounds__(1024) void k_scan(const int* __restrict__ deg, int* __restrict__ off) {
  __shared__ int wsum[16];
  int t = threadIdx.x;
  const int slab = (kN + 1023) / 1024;   // 49
  int lo = t * slab, hi = min(lo + slab, kN);
  int s = 0;
  for (int i = lo; i < hi; ++i) s += deg[i];
  int incl = s;
#pragma unroll
  for (int d = 1; d < 64; d <<= 1) {
    int v = __shfl_up(incl, d);
    if ((t & 63) >= d) incl += v;
  }
  if ((t & 63) == 63) wsum[t >> 6] = incl;
  __syncthreads();
  if (t == 0) {
    int run = 0;
#pragma unroll
    for (int i = 0; i < 16; ++i) { int tmp = wsum[i]; wsum[i] = run; run += tmp; }
  }
  __syncthreads();
  int base = wsum[t >> 6] + incl - s;   // exclusive prefix of this thread's slab
  for (int i = lo; i < hi; ++i) { off[i] = base; base += deg[i]; }
  if (t == 1023) off[kN] = base;
}

// ---- per-(rel,dst) group cursors: cur[r*N+dst] = off[dst] + prefix_r(cnt) ----
__global__ void k_grp(const int* __restrict__ off, const int* __restrict__ cnt,
                      int* __restrict__ cur) {
  int t = blockIdx.x * blockDim.x + threadIdx.x;
  if (t >= kN) return;
  int o = off[t];
#pragma unroll
  for (int r = 0; r < kR; ++r) { cur[r * kN + t] = o; o += cnt[r * kN + t]; }
}

// ---- fill CSR edge records (u16 src), grouped (dst, rel) ----
__global__ void k_fill(const int* __restrict__ ei, const float* __restrict__ ea,
                       int* __restrict__ cur, unsigned short* __restrict__ ebuf) {
  int e = blockIdx.x * blockDim.x + threadIdx.x;
  if (e >= kE) return;
  int src = ei[e];
  int dst = ei[kE + e];
  int rel = (int)ea[(size_t)e * 5 + 4];
  if ((unsigned)dst >= (unsigned)kN || (unsigned)rel >= (unsigned)kR) return;
  int pos = atomicAdd(&cur[rel * kN + dst], 1);
  ebuf[pos] = (unsigned short)src;
}

// ---- aggregation: 1 wave per dst; mean x[src] per relation -> A cols 0..2047 (nontemporal) ----
__global__ __launch_bounds__(256) void k_agg(const unsigned short* __restrict__ ebuf,
                                             const int* __restrict__ off,
                                             const int* __restrict__ cnt,
                                             unsigned short* A) {
  int dst = blockIdx.x * 4 + (threadIdx.x >> 6);
  if (dst >= kN) return;
  int lane = threadIdx.x & 63;
  int e = off[dst];
  const unsigned short* xcols = A + 2048 + lane * 4;   // x region of A
  unsigned short* mrow = A + (size_t)dst * kK + lane * 4;
#pragma unroll
  for (int r = 0; r < kR; ++r) {
    int c = cnt[r * kN + dst];
    float s0 = 0.f, s1 = 0.f, s2 = 0.f, s3 = 0.f;
    for (int k = 0; k < c; ++k) {
      int src = ebuf[e + k];
      ushort4 v = *(const ushort4*)(xcols + (size_t)src * kK);
      s0 += bf2f(v.x); s1 += bf2f(v.y); s2 += bf2f(v.z); s3 += bf2f(v.w);
    }
    e += c;
    float sc = c > 0 ? 1.f / (float)c : 0.f;
    unsigned lo = (unsigned)f2bf(s0 * sc) | ((unsigned)f2bf(s1 * sc) << 16);
    unsigned hi = (unsigned)f2bf(s2 * sc) | ((unsigned)f2bf(s3 * sc) << 16);
    u32x2 pk = {lo, hi};
    __builtin_nontemporal_store(pk, (u32x2*)(mrow + r * 256));   // don't evict x from L3
  }
}

// ---- GEMM [kMP x 2304] @ [2304 x 256] -> d_out f32 (+bias) ----
__global__ __launch_bounds__(256) void k_gemm(const unsigned short* __restrict__ A,
                                              const unsigned short* __restrict__ wbfT,
                                              float* __restrict__ out,
                                              const float* __restrict__ bias) {
  __shared__ __align__(16) unsigned short As[128 * 64];  // [row][k]
  __shared__ __align__(16) unsigned short Bs[128 * 64];  // [col][k]
  const int tid = threadIdx.x;
  const int lane = tid & 63, wv = tid >> 6;
  const int n0 = blockIdx.x * 128, m0 = blockIdx.y * 128;
  const int wm = wv >> 1, wn = wv & 1;  // 2x2 wave grid, 64x64 out each
  f32x4 acc[4][4] = {};

  const int srow = (lane >> 3);        // 0..7
  const int skk  = (lane & 7) * 8;     // 0..56
  for (int kt = 0; kt < kK / 64; ++kt) {
    const int kb = kt * 64;
#pragma unroll
    for (int c = 0; c < 4; ++c) {
      int row = c * 32 + wv * 8 + srow;
      gload16(A    + (size_t)(m0 + row) * kK + kb + skk, &As[c * 2048 + wv * 512]);
      gload16(wbfT + (size_t)(n0 + row) * kK + kb + skk, &Bs[c * 2048 + wv * 512]);
    }
    __syncthreads();
#pragma unroll
    for (int kk = 0; kk < 64; kk += 32) {
      const int koff = kk + (lane >> 4) * 8;
      bf16x8 a[4], b[4];
#pragma unroll
      for (int i = 0; i < 4; ++i) {
        a[i] = *(const bf16x8*)&As[(wm * 64 + i * 16 + (lane & 15)) * 64 + koff];
        b[i] = *(const bf16x8*)&Bs[(wn * 64 + i * 16 + (lane & 15)) * 64 + koff];
      }
#pragma unroll
      for (int i = 0; i < 4; ++i)
#pragma unroll
        for (int j = 0; j < 4; ++j)
          acc[i][j] = __builtin_amdgcn_mfma_f32_16x16x32_bf16(a[i], b[j], acc[i][j], 0, 0, 0);
    }
    __syncthreads();
  }

  // C/D layout: col = lane&15, row = (lane>>4)*4 + r
#pragma unroll
  for (int i = 0; i < 4; ++i)
#pragma unroll
    for (int j = 0; j < 4; ++j) {
      int col = n0 + wn * 64 + j * 16 + (lane & 15);
      int rb  = m0 + wm * 64 + i * 16 + (lane >> 4) * 4;
      float bv = bias[col];
#pragma unroll
      for (int r = 0; r < 4; ++r) {
        int row = rb + r;
        if (row < kN) out[(size_t)row * kC + col] = acc[i][j][r] + bv;
      }
    }
}

// ---- BN column stats ----
__global__ void k_stats(const float* __restrict__ h, float* __restrict__ cs, float* __restrict__ csq) {
  int col = threadIdx.x;  // 256
  float s = 0.f, ss = 0.f;
  for (int row = blockIdx.x; row < kN; row += gridDim.x) {
    float v = h[(size_t)row * kC + col];
    s += v; ss += v * v;
  }
  atomicAdd(&cs[col], s);
  atomicAdd(&csq[col], ss);
}

// ---- BN normalize + PReLU + residual ----
__global__ void k_final(float* __restrict__ h, const float* __restrict__ x,
                        const float* __restrict__ cs, const float* __restrict__ csq,
                        const float* __restrict__ gamma, const float* __restrict__ beta,
                        const float* __restrict__ prelu) {
  int idx = (blockIdx.x * blockDim.x + threadIdx.x) * 4;
  if (idx >= kN * kC) return;
  int col = idx & 255;
  const float inv_n = 1.0f / (float)kN;
  float a = prelu[0];
  float4 hv = *(float4*)(h + idx);
  float4 xv = *(const float4*)(x + idx);
  float hr[4] = {hv.x, hv.y, hv.z, hv.w};
  float xr[4] = {xv.x, xv.y, xv.z, xv.w};
#pragma unroll
  for (int j = 0; j < 4; ++j) {
    int c = col + j;
    float mu  = cs[c] * inv_n;
    float var = csq[c] * inv_n - mu * mu;
    float k   = gamma[c] * rsqrtf(var + 1e-5f);
    float v   = (hr[j] - mu) * k + beta[c];
    v = v > 0.f ? v : a * v;
    hr[j] = v + xr[j];
  }
  *(float4*)(h + idx) = make_float4(hr[0], hr[1], hr[2], hr[3]);
}

extern "C" void kernel_launch(void* const* d_in, const int* in_sizes, int n_in,
                              void* d_out, int out_size, void* d_ws, size_t ws_size,
                              hipStream_t stream) {
  const float* x     = (const float*)d_in[0];
  const int*   ei    = (const int*)d_in[1];     // int64 in ref -> int32 from harness
  const float* ea    = (const float*)d_in[2];
  const float* W     = (const float*)d_in[3];
  const float* root  = (const float*)d_in[4];
  const float* bias  = (const float*)d_in[5];
  const float* gamma = (const float*)d_in[6];
  const float* beta  = (const float*)d_in[7];
  const float* prelu = (const float*)d_in[8];
  float* out = (float*)d_out;
  char* ws = (char*)d_ws;

  size_t o = 0;
  auto alloc = [&](size_t sz) { size_t r = o; o += (sz + 255) & ~(size_t)255; return r; };
  size_t a_o   = alloc((size_t)kMP * kK * 2);       // 230.6 MB
  size_t wbf_o = alloc((size_t)kC * kK * 2);        // 1.2 MB
  size_t cnt_o = alloc((size_t)kR * kN * 4);        // 1.6 MB
  size_t deg_o = alloc((size_t)kN * 4);
  size_t cs_o  = alloc(256 * 4);
  size_t csq_o = alloc(256 * 4);
  size_t zend  = o;                                 // end of must-zero region
  size_t off_o = alloc((size_t)(kN + 1) * 4);
  size_t cur_o = alloc((size_t)kR * kN * 4);
  size_t eb_o  = alloc((size_t)kE * 2);             // u16 src records
  if (o > ws_size) {
    fprintf(stderr, "[RGCN kernel] ws too small: need %zu have %zu\n", o, ws_size);
    return;
  }

  unsigned short* A    = (unsigned short*)(ws + a_o);
  unsigned short* wbfT = (unsigned short*)(ws + wbf_o);
  int*   cnt  = (int*)(ws + cnt_o);
  int*   deg  = (int*)(ws + deg_o);
  float* cs   = (float*)(ws + cs_o);
  float* csq  = (float*)(ws + csq_o);
  int*   offp = (int*)(ws + off_o);
  int*   cur  = (int*)(ws + cur_o);
  unsigned short* ebuf = (unsigned short*)(ws + eb_o);

  hipMemsetAsync(ws + cnt_o, 0, zend - cnt_o, stream);                       // cnt/deg/cs/csq
  hipMemsetAsync(ws + a_o + (size_t)kN * kK * 2, 0,
                 (size_t)(kMP - kN) * kK * 2, stream);                       // A pad rows
  k_count<<<(kE + 255) / 256, 256, 0, stream>>>(ei, ea, cnt, deg);
  k_convert_x<<<(kN * kC / 4) / 256, 256, 0, stream>>>(x, A);
  k_convert_w<<<(kC * kK + 255) / 256, 256, 0, stream>>>(W, root, wbfT);
  k_scan<<<1, 1024, 0, stream>>>(deg, offp);
  k_grp<<<(kN + 255) / 256, 256, 0, stream>>>(offp, cnt, cur);
  k_fill<<<(kE + 255) / 256, 256, 0, stream>>>(ei, ea, cur, ebuf);
  k_agg<<<(kN + 3) / 4, 256, 0, stream>>>(ebuf, offp, cnt, A);
  k_gemm<<<dim3(kC / 128, kMP / 128), 256, 0, stream>>>(A, wbfT, out, bias);
  k_stats<<<512, 256, 0, stream>>>(out, cs, csq);
  k_final<<<(kN * kC / 4) / 256, 256, 0, stream>>>(out, x, cs, csq, gamma, beta, prelu);
}